// Round 1
// baseline (2973.116 us; speedup 1.0000x reference)
//
#include <hip/hip_runtime.h>
#include <cmath>

#define N_NODES 50000
#define DIM 128
#define DOUT 64

// ---------------------------------------------------------------------------
// SpMM: y[rows[e], :] += vals[e] * x[cols[e], :]
// 32 threads per edge, each thread handles 4 contiguous floats (float4 gather
// + 4 f32 hardware atomic adds). Coalesced 512B read per edge.
// ---------------------------------------------------------------------------
__global__ __launch_bounds__(256) void spmm_kernel(
    const int* __restrict__ rows,
    const int* __restrict__ cols,
    const float* __restrict__ vals,
    const float* __restrict__ x,
    float* __restrict__ y,
    int nE) {
  long long i = (long long)blockIdx.x * blockDim.x + threadIdx.x;
  long long total = (long long)nE * 32;
  if (i >= total) return;
  int e = (int)(i >> 5);
  int c = ((int)i & 31) << 2;  // float offset within the 128-wide row
  int r = rows[e];
  int cl = cols[e];
  float v = vals[e];
  const float4 xv = *reinterpret_cast<const float4*>(x + (long long)cl * DIM + c);
  float* dst = y + (long long)r * DIM + c;
  // unsafeAtomicAdd -> global_atomic_add_f32 (no CAS loop). Denormal flush ok.
  unsafeAtomicAdd(dst + 0, v * xv.x);
  unsafeAtomicAdd(dst + 1, v * xv.y);
  unsafeAtomicAdd(dst + 2, v * xv.z);
  unsafeAtomicAdd(dst + 3, v * xv.w);
}

// ---------------------------------------------------------------------------
// GEMM1 + ReLU: y = relu(x @ W), x [N,128], W [128,128].
// Block = 256 threads: 2 row-groups x 128 cols; each thread computes 4 rows
// for its col -> 8 rows per block. W column values reused across 4 rows in
// registers; x reads are wave-broadcast (same addr across the 128 lanes of a
// row-group) and L1-resident; W reads are coalesced across cols.
// ---------------------------------------------------------------------------
__global__ __launch_bounds__(256) void gemm_relu_kernel(
    const float* __restrict__ x,
    const float* __restrict__ W,
    float* __restrict__ y) {
  const int col = threadIdx.x & (DIM - 1);
  const int rg  = threadIdx.x >> 7;  // 0..1
  const int r0  = blockIdx.x * 8 + rg * 4;
  const float* x0 = x + (long long)r0 * DIM;
  float acc0 = 0.f, acc1 = 0.f, acc2 = 0.f, acc3 = 0.f;
#pragma unroll 8
  for (int k = 0; k < DIM; ++k) {
    float w = W[k * DIM + col];
    acc0 += x0[k] * w;
    acc1 += x0[DIM + k] * w;
    acc2 += x0[2 * DIM + k] * w;
    acc3 += x0[3 * DIM + k] * w;
  }
  float* y0 = y + (long long)r0 * DIM + col;
  y0[0]       = fmaxf(acc0, 0.f);
  y0[DIM]     = fmaxf(acc1, 0.f);
  y0[2 * DIM] = fmaxf(acc2, 0.f);
  y0[3 * DIM] = fmaxf(acc3, 0.f);
}

// ---------------------------------------------------------------------------
// GEMM2 + row softmax: out = softmax(x @ W2, axis=1), x [N,128], W2 [128,64].
// One 64-lane wave per output row; lane = output col. Wave shuffle reduction
// for max and sum (all 64 lanes participate -- wave64).
// ---------------------------------------------------------------------------
__global__ __launch_bounds__(256) void gemm_softmax_kernel(
    const float* __restrict__ x,
    const float* __restrict__ W,
    float* __restrict__ out) {
  const int lane = threadIdx.x & 63;
  const int wr   = threadIdx.x >> 6;  // 0..3 waves per block
  const int row  = blockIdx.x * 4 + wr;
  const float* xr = x + (long long)row * DIM;
  float acc = 0.f;
#pragma unroll 8
  for (int k = 0; k < DIM; ++k)
    acc += xr[k] * W[k * DOUT + lane];
  // wave softmax over 64 lanes
  float m = acc;
  for (int o = 32; o >= 1; o >>= 1)
    m = fmaxf(m, __shfl_xor(m, o));
  float ev = expf(acc - m);
  float s = ev;
  for (int o = 32; o >= 1; o >>= 1)
    s += __shfl_xor(s, o);
  out[(long long)row * DOUT + lane] = ev / s;
}

extern "C" void kernel_launch(void* const* d_in, const int* in_sizes, int n_in,
                              void* d_out, int out_size, void* d_ws, size_t ws_size,
                              hipStream_t stream) {
  const float* emb   = (const float*)d_in[0];
  const int*   arows = (const int*)d_in[1];
  const int*   acols = (const int*)d_in[2];
  const float* avals = (const float*)d_in[3];
  const float* W1    = (const float*)d_in[4];
  const float* W2    = (const float*)d_in[5];
  float* out = (float*)d_out;
  const int E = in_sizes[1];

  const size_t hbytes = (size_t)N_NODES * DIM * sizeof(float);  // 25.6 MB
  float* h0 = (float*)d_ws;                                     // spmm1 out
  float* h1 = (float*)((char*)d_ws + hbytes);                   // relu(h0@W1)
  float* h2 = (float*)((char*)d_ws + 2 * hbytes);               // spmm2 out

  // ws is re-poisoned to 0xAA before every launch -> must zero accumulators.
  hipMemsetAsync(h0, 0, hbytes, stream);
  hipMemsetAsync(h2, 0, hbytes, stream);

  const long long total = (long long)E * 32;
  const int sblocks = (int)((total + 255) / 256);

  spmm_kernel<<<sblocks, 256, 0, stream>>>(arows, acols, avals, emb, h0, E);
  gemm_relu_kernel<<<N_NODES / 8, 256, 0, stream>>>(h0, W1, h1);
  spmm_kernel<<<sblocks, 256, 0, stream>>>(arows, acols, avals, h1, h2, E);
  gemm_softmax_kernel<<<N_NODES / 4, 256, 0, stream>>>(h2, W2, out);
}

// Round 2
// 573.768 us; speedup vs baseline: 5.1817x; 5.1817x over previous
//
#include <hip/hip_runtime.h>
#include <cmath>

#define N_NODES 50000
#define DIM 128
#define DOUT 64

// ===========================================================================
// CSR build: histogram -> single-block scan -> scatter.
// rows/cols/vals are restored pristine before every launch, so we rebuild the
// CSR every call (same work every call; graph-capture safe).
// ===========================================================================

__global__ __launch_bounds__(256) void hist_kernel(
    const int* __restrict__ rows, int* __restrict__ deg, int E) {
  int e = blockIdx.x * blockDim.x + threadIdx.x;
  if (e < E) atomicAdd(&deg[rows[e]], 1);
}

// Single-block exclusive scan of deg[50000] -> rowptr[50001] and cursor copy.
// 256 threads x 8 elems/thread per chunk => 25 chunks.
__global__ __launch_bounds__(256) void scan_kernel(
    const int* __restrict__ deg, int* __restrict__ rowptr,
    int* __restrict__ cursor) {
  __shared__ int ssum[256];
  __shared__ int s_carry;
  if (threadIdx.x == 0) s_carry = 0;
  __syncthreads();
  const int CH = 8;
  for (int base = 0; base < N_NODES; base += 256 * CH) {
    int d[CH];
    int idx0 = base + threadIdx.x * CH;
    int local = 0;
#pragma unroll
    for (int j = 0; j < CH; ++j) {
      int idx = idx0 + j;
      d[j] = (idx < N_NODES) ? deg[idx] : 0;
      local += d[j];
    }
    ssum[threadIdx.x] = local;
    __syncthreads();
    // inclusive block scan over ssum
    for (int o = 1; o < 256; o <<= 1) {
      int t = (threadIdx.x >= (unsigned)o) ? ssum[threadIdx.x - o] : 0;
      __syncthreads();
      ssum[threadIdx.x] += t;
      __syncthreads();
    }
    int pre = s_carry + ssum[threadIdx.x] - local;  // exclusive prefix
    __syncthreads();  // everyone has read s_carry before thread 255 bumps it
    if (threadIdx.x == 255) s_carry += ssum[255];
#pragma unroll
    for (int j = 0; j < CH; ++j) {
      int idx = idx0 + j;
      if (idx < N_NODES) { rowptr[idx] = pre; cursor[idx] = pre; }
      pre += d[j];
    }
    __syncthreads();
  }
  if (threadIdx.x == 0) rowptr[N_NODES] = s_carry;
}

// Scatter edges into row-sorted order, packed (col, val) as int2 (one 8B
// broadcast load in the SpMM inner loop instead of two 4B loads).
__global__ __launch_bounds__(256) void scatter_kernel(
    const int* __restrict__ rows, const int* __restrict__ cols,
    const float* __restrict__ vals, int* __restrict__ cursor,
    int2* __restrict__ edges, int E) {
  int e = blockIdx.x * blockDim.x + threadIdx.x;
  if (e < E) {
    int p = atomicAdd(&cursor[rows[e]], 1);
    edges[p] = make_int2(cols[e], __float_as_int(vals[e]));
  }
}

// ===========================================================================
// CSR SpMM: one 64-lane wave per output row, float2 per lane (128 cols).
// Edge metadata is a wave-uniform 8B load (hardware broadcast, L1-resident);
// x[col] gather is a coalesced 512B row read, mostly L2/L3-resident.
// Zero atomics; each output row written exactly once.
// ===========================================================================
__global__ __launch_bounds__(256) void spmm_csr_kernel(
    const int* __restrict__ rowptr, const int2* __restrict__ edges,
    const float* __restrict__ x, float* __restrict__ y) {
  const int row = blockIdx.x * 4 + (threadIdx.x >> 6);
  const int lane = threadIdx.x & 63;
  const int beg = rowptr[row];
  const int end = rowptr[row + 1];
  const float2* __restrict__ x2 = reinterpret_cast<const float2*>(x);
  float accx = 0.f, accy = 0.f;
  int i = beg;
  // unroll by 2: two independent gathers in flight
  for (; i + 2 <= end; i += 2) {
    int2 e0 = edges[i];
    int2 e1 = edges[i + 1];
    float2 xv0 = x2[(long long)e0.x * 64 + lane];
    float2 xv1 = x2[(long long)e1.x * 64 + lane];
    float v0 = __int_as_float(e0.y);
    float v1 = __int_as_float(e1.y);
    accx += v0 * xv0.x; accy += v0 * xv0.y;
    accx += v1 * xv1.x; accy += v1 * xv1.y;
  }
  if (i < end) {
    int2 e0 = edges[i];
    float2 xv0 = x2[(long long)e0.x * 64 + lane];
    float v0 = __int_as_float(e0.y);
    accx += v0 * xv0.x; accy += v0 * xv0.y;
  }
  reinterpret_cast<float2*>(y)[(long long)row * 64 + lane] =
      make_float2(accx, accy);
}

// ===========================================================================
// GEMM1 + ReLU: y = relu(x @ W), x [N,128], W [128,128].
// ===========================================================================
__global__ __launch_bounds__(256) void gemm_relu_kernel(
    const float* __restrict__ x, const float* __restrict__ W,
    float* __restrict__ y) {
  const int col = threadIdx.x & (DIM - 1);
  const int rg  = threadIdx.x >> 7;  // 0..1
  const int r0  = blockIdx.x * 8 + rg * 4;
  const float* x0 = x + (long long)r0 * DIM;
  float acc0 = 0.f, acc1 = 0.f, acc2 = 0.f, acc3 = 0.f;
#pragma unroll 8
  for (int k = 0; k < DIM; ++k) {
    float w = W[k * DIM + col];
    acc0 += x0[k] * w;
    acc1 += x0[DIM + k] * w;
    acc2 += x0[2 * DIM + k] * w;
    acc3 += x0[3 * DIM + k] * w;
  }
  float* y0 = y + (long long)r0 * DIM + col;
  y0[0]       = fmaxf(acc0, 0.f);
  y0[DIM]     = fmaxf(acc1, 0.f);
  y0[2 * DIM] = fmaxf(acc2, 0.f);
  y0[3 * DIM] = fmaxf(acc3, 0.f);
}

// ===========================================================================
// GEMM2 + row softmax: out = softmax(x @ W2, axis=1), x [N,128], W2 [128,64].
// One 64-lane wave per row; lane = output col; wave shuffle reductions.
// ===========================================================================
__global__ __launch_bounds__(256) void gemm_softmax_kernel(
    const float* __restrict__ x, const float* __restrict__ W,
    float* __restrict__ out) {
  const int lane = threadIdx.x & 63;
  const int wr   = threadIdx.x >> 6;
  const int row  = blockIdx.x * 4 + wr;
  const float* xr = x + (long long)row * DIM;
  float acc = 0.f;
#pragma unroll 8
  for (int k = 0; k < DIM; ++k)
    acc += xr[k] * W[k * DOUT + lane];
  float m = acc;
  for (int o = 32; o >= 1; o >>= 1)
    m = fmaxf(m, __shfl_xor(m, o));
  float ev = expf(acc - m);
  float s = ev;
  for (int o = 32; o >= 1; o >>= 1)
    s += __shfl_xor(s, o);
  out[(long long)row * DOUT + lane] = ev / s;
}

extern "C" void kernel_launch(void* const* d_in, const int* in_sizes, int n_in,
                              void* d_out, int out_size, void* d_ws, size_t ws_size,
                              hipStream_t stream) {
  const float* emb   = (const float*)d_in[0];
  const int*   arows = (const int*)d_in[1];
  const int*   acols = (const int*)d_in[2];
  const float* avals = (const float*)d_in[3];
  const float* W1    = (const float*)d_in[4];
  const float* W2    = (const float*)d_in[5];
  float* out = (float*)d_out;
  const int E = in_sizes[1];

  // ---- workspace layout (~58.3 MB) ----
  const size_t hbytes = (size_t)N_NODES * DIM * sizeof(float);  // 25.6 MB
  char* p = (char*)d_ws;
  float* h0     = (float*)p;                 p += hbytes;        // spmm out (reused for layer 2)
  float* h1     = (float*)p;                 p += hbytes;        // relu(h0@W1)
  int2*  edges  = (int2*)p;                  p += (size_t)E * sizeof(int2);
  int*   deg    = (int*)p;                   p += (size_t)N_NODES * sizeof(int);
  int*   rowptr = (int*)p;                   p += (size_t)(N_NODES + 1) * sizeof(int);
  int*   cursor = (int*)p;

  // deg must start at zero (ws is poisoned 0xAA each call)
  hipMemsetAsync(deg, 0, (size_t)N_NODES * sizeof(int), stream);

  const int eblocks = (E + 255) / 256;

  // CSR build (once; used by both SpMMs)
  hist_kernel<<<eblocks, 256, 0, stream>>>(arows, deg, E);
  scan_kernel<<<1, 256, 0, stream>>>(deg, rowptr, cursor);
  scatter_kernel<<<eblocks, 256, 0, stream>>>(arows, acols, avals, cursor, edges, E);

  // layer 1
  spmm_csr_kernel<<<N_NODES / 4, 256, 0, stream>>>(rowptr, edges, emb, h0);
  gemm_relu_kernel<<<N_NODES / 8, 256, 0, stream>>>(h0, W1, h1);
  // layer 2 (h0's buffer is dead after gemm1 -> reuse it for spmm2 output)
  spmm_csr_kernel<<<N_NODES / 4, 256, 0, stream>>>(rowptr, edges, h1, h0);
  gemm_softmax_kernel<<<N_NODES / 4, 256, 0, stream>>>(h0, W2, out);
}

// Round 5
// 308.835 us; speedup vs baseline: 9.6269x; 1.8578x over previous
//
#include <hip/hip_runtime.h>
#include <cmath>

#define N_NODES 50000
#define DIM 128
#define DOUT 64
#define SCAN_NB 196  // ceil(50000/256)

typedef float f32x4 __attribute__((ext_vector_type(4)));

// ===========================================================================
// CSR build: histogram -> two-level scan -> scatter.
// Inputs are restored pristine every call, so we rebuild every call.
// ===========================================================================

__global__ __launch_bounds__(256) void hist_kernel(
    const int* __restrict__ rows, int* __restrict__ deg, int E) {
  int e = blockIdx.x * blockDim.x + threadIdx.x;
  if (e < E) atomicAdd(&deg[rows[e]], 1);
}

// per-block inclusive scan of deg -> incl, block totals -> partials
__global__ __launch_bounds__(256) void scan_blk_kernel(
    const int* __restrict__ deg, int* __restrict__ incl,
    int* __restrict__ partials) {
  __shared__ int s[256];
  int i = blockIdx.x * 256 + threadIdx.x;
  int v = (i < N_NODES) ? deg[i] : 0;
  s[threadIdx.x] = v;
  __syncthreads();
  for (int o = 1; o < 256; o <<= 1) {
    int t = (threadIdx.x >= (unsigned)o) ? s[threadIdx.x - o] : 0;
    __syncthreads();
    s[threadIdx.x] += t;
    __syncthreads();
  }
  if (i < N_NODES) incl[i] = s[threadIdx.x];
  if (threadIdx.x == 255) partials[blockIdx.x] = s[255];
}

// single small block: exclusive-scan the 196 partials in place
__global__ __launch_bounds__(256) void scan_part_kernel(
    int* __restrict__ partials, int* __restrict__ rowptr, int E) {
  __shared__ int s[256];
  int v = (threadIdx.x < SCAN_NB) ? partials[threadIdx.x] : 0;
  s[threadIdx.x] = v;
  __syncthreads();
  for (int o = 1; o < 256; o <<= 1) {
    int t = (threadIdx.x >= (unsigned)o) ? s[threadIdx.x - o] : 0;
    __syncthreads();
    s[threadIdx.x] += t;
    __syncthreads();
  }
  if (threadIdx.x < SCAN_NB) partials[threadIdx.x] = s[threadIdx.x] - v;
  if (threadIdx.x == 0) rowptr[N_NODES] = E;
}

// exclusive prefix = incl - deg + block offset -> rowptr & cursor
__global__ __launch_bounds__(256) void scan_add_kernel(
    const int* __restrict__ incl, const int* __restrict__ deg,
    const int* __restrict__ partials, int* __restrict__ rowptr,
    int* __restrict__ cursor) {
  int i = blockIdx.x * 256 + threadIdx.x;
  if (i < N_NODES) {
    int excl = incl[i] - deg[i] + partials[blockIdx.x];
    rowptr[i] = excl;
    cursor[i] = excl;
  }
}

__global__ __launch_bounds__(256) void scatter_kernel(
    const int* __restrict__ rows, const int* __restrict__ cols,
    const float* __restrict__ vals, int* __restrict__ cursor,
    int2* __restrict__ edges, int E) {
  int e = blockIdx.x * blockDim.x + threadIdx.x;
  if (e < E) {
    int p = atomicAdd(&cursor[rows[e]], 1);
    edges[p] = make_int2(cols[e], __float_as_int(vals[e]));
  }
}

// ===========================================================================
// Dense GEMM: y[M,N] = x[M,128] @ W[128,N], N in {128,64}.
// Block tile 64 rows x 64 cols (grid.y = N/64). W-panel (32KB) + x-tile
// (64x132 padded, 33KB) in LDS. Thread = 4 rows x 4 cols, k-unroll 4:
// 64 FMA per 8 ds_read_b128. Pad 132 kills the 4-way row-bank aliasing.
// ===========================================================================
template <int N>
__global__ __launch_bounds__(256) void gemm_kernel(
    const float* __restrict__ x, const float* __restrict__ W,
    float* __restrict__ y, int M) {
  __shared__ float sW[128 * 64];   // sW[k*64 + c]
  __shared__ float sX[64 * 132];   // sX[r*132 + k]
  const int cb = blockIdx.y;
  const int row0 = blockIdx.x * 64;

  for (int i = threadIdx.x; i < 128 * 16; i += 256) {
    int k = i >> 4, c4 = i & 15;
    reinterpret_cast<f32x4*>(sW)[k * 16 + c4] =
        reinterpret_cast<const f32x4*>(W)[k * (N / 4) + cb * 16 + c4];
  }
  for (int i = threadIdx.x; i < 64 * 32; i += 256) {
    int r = i >> 5, c4 = i & 31;
    int gr = row0 + r;
    if (gr >= M) gr = M - 1;
    f32x4 v = reinterpret_cast<const f32x4*>(x + (size_t)gr * 128)[c4];
    *reinterpret_cast<f32x4*>(&sX[r * 132 + c4 * 4]) = v;
  }
  __syncthreads();

  const int ct = threadIdx.x & 15;   // -> cols c0..c0+3
  const int rt = threadIdx.x >> 4;   // -> rows rt*4..rt*4+3
  const int c0 = ct * 4;
  float acc[4][4] = {};

  for (int k = 0; k < 128; k += 4) {
    f32x4 xa[4], wb[4];
#pragma unroll
    for (int r = 0; r < 4; ++r)
      xa[r] = *reinterpret_cast<const f32x4*>(&sX[(rt * 4 + r) * 132 + k]);
#pragma unroll
    for (int kk = 0; kk < 4; ++kk)
      wb[kk] = *reinterpret_cast<const f32x4*>(&sW[(k + kk) * 64 + c0]);
#pragma unroll
    for (int r = 0; r < 4; ++r)
#pragma unroll
      for (int c = 0; c < 4; ++c)
#pragma unroll
        for (int kk = 0; kk < 4; ++kk)
          acc[r][c] += xa[r][kk] * wb[kk][c];
  }

#pragma unroll
  for (int r = 0; r < 4; ++r) {
    int gr = row0 + rt * 4 + r;
    if (gr < M) {
      f32x4 v = {acc[r][0], acc[r][1], acc[r][2], acc[r][3]};
      *reinterpret_cast<f32x4*>(y + (size_t)gr * N + cb * 64 + c0) = v;
    }
  }
}

// ===========================================================================
// SpMM (128-wide) + ReLU: h[row,:] = relu(sum_e val_e * x[col_e,:]).
// One 64-lane wave per row, float2/lane, 4 gathers in flight.
// ===========================================================================
__global__ __launch_bounds__(256) void spmm_relu_kernel(
    const int* __restrict__ rowptr, const int2* __restrict__ edges,
    const float* __restrict__ x, float* __restrict__ y) {
  const int row = blockIdx.x * 4 + (threadIdx.x >> 6);
  const int lane = threadIdx.x & 63;
  const int beg = rowptr[row];
  const int end = rowptr[row + 1];
  const float2* __restrict__ x2 = reinterpret_cast<const float2*>(x);
  float ax = 0.f, ay = 0.f;
  int i = beg;
  for (; i + 4 <= end; i += 4) {
    int2 e0 = edges[i], e1 = edges[i + 1], e2 = edges[i + 2], e3 = edges[i + 3];
    float2 v0 = x2[(size_t)e0.x * 64 + lane];
    float2 v1 = x2[(size_t)e1.x * 64 + lane];
    float2 v2 = x2[(size_t)e2.x * 64 + lane];
    float2 v3 = x2[(size_t)e3.x * 64 + lane];
    float w0 = __int_as_float(e0.y), w1 = __int_as_float(e1.y);
    float w2 = __int_as_float(e2.y), w3 = __int_as_float(e3.y);
    ax += w0 * v0.x + w1 * v1.x + w2 * v2.x + w3 * v3.x;
    ay += w0 * v0.y + w1 * v1.y + w2 * v2.y + w3 * v3.y;
  }
  for (; i < end; ++i) {
    int2 e = edges[i];
    float2 v = x2[(size_t)e.x * 64 + lane];
    float w = __int_as_float(e.y);
    ax += w * v.x;
    ay += w * v.y;
  }
  reinterpret_cast<float2*>(y)[(size_t)row * 64 + lane] =
      make_float2(fmaxf(ax, 0.f), fmaxf(ay, 0.f));
}

// ===========================================================================
// SpMM (64-wide) + row softmax: logits[row,:] = sum_e val_e * t2[col_e,:],
// out = softmax(logits). One wave per row, 1 float/lane, softmax via
// 64-lane shuffle reductions. Gather is 256B/edge (half of layer 1).
// ===========================================================================
__global__ __launch_bounds__(256) void spmm_softmax_kernel(
    const int* __restrict__ rowptr, const int2* __restrict__ edges,
    const float* __restrict__ t2, float* __restrict__ out) {
  const int row = blockIdx.x * 4 + (threadIdx.x >> 6);
  const int lane = threadIdx.x & 63;
  const int beg = rowptr[row];
  const int end = rowptr[row + 1];
  float acc = 0.f;
  int i = beg;
  for (; i + 4 <= end; i += 4) {
    int2 e0 = edges[i], e1 = edges[i + 1], e2 = edges[i + 2], e3 = edges[i + 3];
    float v0 = t2[(size_t)e0.x * 64 + lane];
    float v1 = t2[(size_t)e1.x * 64 + lane];
    float v2 = t2[(size_t)e2.x * 64 + lane];
    float v3 = t2[(size_t)e3.x * 64 + lane];
    acc += __int_as_float(e0.y) * v0 + __int_as_float(e1.y) * v1 +
           __int_as_float(e2.y) * v2 + __int_as_float(e3.y) * v3;
  }
  for (; i < end; ++i) {
    int2 e = edges[i];
    acc += __int_as_float(e.y) * t2[(size_t)e.x * 64 + lane];
  }
  float m = acc;
  for (int o = 32; o >= 1; o >>= 1) m = fmaxf(m, __shfl_xor(m, o));
  float ev = expf(acc - m);
  float s = ev;
  for (int o = 32; o >= 1; o >>= 1) s += __shfl_xor(s, o);
  out[(size_t)row * 64 + lane] = ev / s;
}

extern "C" void kernel_launch(void* const* d_in, const int* in_sizes, int n_in,
                              void* d_out, int out_size, void* d_ws, size_t ws_size,
                              hipStream_t stream) {
  const float* emb   = (const float*)d_in[0];
  const int*   arows = (const int*)d_in[1];
  const int*   acols = (const int*)d_in[2];
  const float* avals = (const float*)d_in[3];
  const float* W1    = (const float*)d_in[4];
  const float* W2    = (const float*)d_in[5];
  float* out = (float*)d_out;
  const int E = in_sizes[1];

  // ---- workspace layout (~58.4 MB) ----
  const size_t hbytes = (size_t)N_NODES * DIM * sizeof(float);  // 25.6 MB
  char* p = (char*)d_ws;
  float* bufA   = (float*)p; p += hbytes;                    // t1, later t2
  float* bufB   = (float*)p; p += hbytes;                    // h
  int2*  edges  = (int2*)p;  p += (size_t)E * sizeof(int2);  // 6.4 MB
  int*   deg    = (int*)p;   p += (size_t)N_NODES * sizeof(int);
  int*   rowptr = (int*)p;   p += (size_t)(N_NODES + 1) * sizeof(int);
  int*   cursor = (int*)p;
  // scan temps alias the edges buffer (edges written only after scan is done)
  int* incl     = (int*)edges;
  int* partials = ((int*)edges) + N_NODES;

  hipMemsetAsync(deg, 0, (size_t)N_NODES * sizeof(int), stream);

  const int eblocks = (E + 255) / 256;

  // CSR build
  hist_kernel<<<eblocks, 256, 0, stream>>>(arows, deg, E);
  scan_blk_kernel<<<SCAN_NB, 256, 0, stream>>>(deg, incl, partials);
  scan_part_kernel<<<1, 256, 0, stream>>>(partials, rowptr, E);
  scan_add_kernel<<<SCAN_NB, 256, 0, stream>>>(incl, deg, partials, rowptr, cursor);
  scatter_kernel<<<eblocks, 256, 0, stream>>>(arows, acols, avals, cursor, edges, E);

  const int gblocks = (N_NODES + 63) / 64;  // 782

  // layer 1, reassociated: h = relu(A @ (emb @ W1))
  gemm_kernel<128><<<dim3(gblocks, 2), 256, 0, stream>>>(emb, W1, bufA, N_NODES);
  spmm_relu_kernel<<<N_NODES / 4, 256, 0, stream>>>(rowptr, edges, bufA, bufB);
  // layer 2, reassociated: out = softmax(A @ (h @ W2))
  gemm_kernel<64><<<dim3(gblocks, 1), 256, 0, stream>>>(bufB, W2, bufA, N_NODES);
  spmm_softmax_kernel<<<N_NODES / 4, 256, 0, stream>>>(rowptr, edges, bufA, out);
}

// Round 7
// 257.586 us; speedup vs baseline: 11.5422x; 1.1990x over previous
//
#include <hip/hip_runtime.h>
#include <cmath>

#define N_NODES 50000
#define DIM 128
#define DOUT 64
#define SCAN_NB 196  // ceil(50000/256)

typedef float f32x4 __attribute__((ext_vector_type(4)));

// f32 -> bf16 (round-to-nearest-even), packed as ushort
__device__ __forceinline__ unsigned short f2bf(float f) {
  unsigned int u = __float_as_uint(f);
  u = (u + 0x7fffu + ((u >> 16) & 1u)) >> 16;
  return (unsigned short)u;
}
// packed uint = [bf16 lo | bf16 hi] -> two floats
__device__ __forceinline__ float bflo(unsigned int q) {
  return __uint_as_float(q << 16);
}
__device__ __forceinline__ float bfhi(unsigned int q) {
  return __uint_as_float(q & 0xffff0000u);
}

// ===========================================================================
// CSR build: per-edge local offset (atomic hist) -> two-level scan -> scatter
// (no atomic in scatter: pos = rowptr[row] + localoff[e]).
// ===========================================================================

__global__ __launch_bounds__(256) void off_kernel(
    const int* __restrict__ rows, int* __restrict__ deg,
    int* __restrict__ localoff, int E) {
  int e = blockIdx.x * blockDim.x + threadIdx.x;
  if (e < E) localoff[e] = atomicAdd(&deg[rows[e]], 1);
}

// per-block inclusive scan of deg -> incl, block totals -> partials
__global__ __launch_bounds__(256) void scan_blk_kernel(
    const int* __restrict__ deg, int* __restrict__ incl,
    int* __restrict__ partials) {
  __shared__ int s[256];
  int i = blockIdx.x * 256 + threadIdx.x;
  int v = (i < N_NODES) ? deg[i] : 0;
  s[threadIdx.x] = v;
  __syncthreads();
  for (int o = 1; o < 256; o <<= 1) {
    int t = (threadIdx.x >= (unsigned)o) ? s[threadIdx.x - o] : 0;
    __syncthreads();
    s[threadIdx.x] += t;
    __syncthreads();
  }
  if (i < N_NODES) incl[i] = s[threadIdx.x];
  if (threadIdx.x == 255) partials[blockIdx.x] = s[255];
}

// single small block: exclusive-scan the 196 partials in place
__global__ __launch_bounds__(256) void scan_part_kernel(
    int* __restrict__ partials, int* __restrict__ rowptr, int E) {
  __shared__ int s[256];
  int v = (threadIdx.x < SCAN_NB) ? partials[threadIdx.x] : 0;
  s[threadIdx.x] = v;
  __syncthreads();
  for (int o = 1; o < 256; o <<= 1) {
    int t = (threadIdx.x >= (unsigned)o) ? s[threadIdx.x - o] : 0;
    __syncthreads();
    s[threadIdx.x] += t;
    __syncthreads();
  }
  if (threadIdx.x < SCAN_NB) partials[threadIdx.x] = s[threadIdx.x] - v;
  if (threadIdx.x == 0) rowptr[N_NODES] = E;
}

// exclusive prefix = incl - deg + block offset -> rowptr
__global__ __launch_bounds__(256) void scan_add_kernel(
    const int* __restrict__ incl, const int* __restrict__ deg,
    const int* __restrict__ partials, int* __restrict__ rowptr) {
  int i = blockIdx.x * 256 + threadIdx.x;
  if (i < N_NODES)
    rowptr[i] = incl[i] - deg[i] + partials[blockIdx.x];
}

__global__ __launch_bounds__(256) void scatter_kernel(
    const int* __restrict__ rows, const int* __restrict__ cols,
    const float* __restrict__ vals, const int* __restrict__ rowptr,
    const int* __restrict__ localoff, int2* __restrict__ edges, int E) {
  int e = blockIdx.x * blockDim.x + threadIdx.x;
  if (e < E) {
    int p = rowptr[rows[e]] + localoff[e];
    edges[p] = make_int2(cols[e], __float_as_int(vals[e]));
  }
}

// ===========================================================================
// Dense GEMM: y[M,N](bf16) = x[M,128](f32) @ W[128,N](f32), N in {128,64}.
// Block tile 64 rows x 64 cols (grid.y = N/64). W-panel (32KB) + x-tile
// (64x132 padded, 33KB) in LDS. Thread = 4 rows x 4 cols, k-unroll 4.
// Epilogue converts to bf16 (halves gather bytes of the following SpMM).
// ===========================================================================
template <int N>
__global__ __launch_bounds__(256) void gemm_kernel(
    const float* __restrict__ x, const float* __restrict__ W,
    unsigned short* __restrict__ y, int M) {
  __shared__ float sW[128 * 64];   // sW[k*64 + c]
  __shared__ float sX[64 * 132];   // sX[r*132 + k]
  const int cb = blockIdx.y;
  const int row0 = blockIdx.x * 64;

  for (int i = threadIdx.x; i < 128 * 16; i += 256) {
    int k = i >> 4, c4 = i & 15;
    reinterpret_cast<f32x4*>(sW)[k * 16 + c4] =
        reinterpret_cast<const f32x4*>(W)[k * (N / 4) + cb * 16 + c4];
  }
  for (int i = threadIdx.x; i < 64 * 32; i += 256) {
    int r = i >> 5, c4 = i & 31;
    int gr = row0 + r;
    if (gr >= M) gr = M - 1;
    f32x4 v = reinterpret_cast<const f32x4*>(x + (size_t)gr * 128)[c4];
    *reinterpret_cast<f32x4*>(&sX[r * 132 + c4 * 4]) = v;
  }
  __syncthreads();

  const int ct = threadIdx.x & 15;   // -> cols c0..c0+3
  const int rt = threadIdx.x >> 4;   // -> rows rt*4..rt*4+3
  const int c0 = ct * 4;
  float acc[4][4] = {};

  for (int k = 0; k < 128; k += 4) {
    f32x4 xa[4], wb[4];
#pragma unroll
    for (int r = 0; r < 4; ++r)
      xa[r] = *reinterpret_cast<const f32x4*>(&sX[(rt * 4 + r) * 132 + k]);
#pragma unroll
    for (int kk = 0; kk < 4; ++kk)
      wb[kk] = *reinterpret_cast<const f32x4*>(&sW[(k + kk) * 64 + c0]);
#pragma unroll
    for (int r = 0; r < 4; ++r)
#pragma unroll
      for (int c = 0; c < 4; ++c)
#pragma unroll
        for (int kk = 0; kk < 4; ++kk)
          acc[r][c] += xa[r][kk] * wb[kk][c];
  }

#pragma unroll
  for (int r = 0; r < 4; ++r) {
    int gr = row0 + rt * 4 + r;
    if (gr < M) {
      ushort4 v = {f2bf(acc[r][0]), f2bf(acc[r][1]),
                   f2bf(acc[r][2]), f2bf(acc[r][3])};
      *reinterpret_cast<ushort4*>(y + (size_t)gr * N + cb * 64 + c0) = v;
    }
  }
}

// ===========================================================================
// SpMM (128-wide, bf16 table) + ReLU: h[row,:] = relu(sum val_e * t1[col_e,:]).
// One 64-lane wave per row; each lane loads a packed uint (2 bf16 cols):
// 256B/edge fully coalesced. h written in f32 (read once by gemm<64>).
// ===========================================================================
__global__ __launch_bounds__(256) void spmm_relu_kernel(
    const int* __restrict__ rowptr, const int2* __restrict__ edges,
    const unsigned int* __restrict__ t1q,  // [N_NODES][64] packed bf16x2
    float* __restrict__ y) {
  const int row = blockIdx.x * 4 + (threadIdx.x >> 6);
  const int lane = threadIdx.x & 63;
  const int beg = rowptr[row];
  const int end = rowptr[row + 1];
  float ax = 0.f, ay = 0.f;
  int i = beg;
  for (; i + 4 <= end; i += 4) {
    int2 e0 = edges[i], e1 = edges[i + 1], e2 = edges[i + 2], e3 = edges[i + 3];
    unsigned int q0 = t1q[(size_t)e0.x * 64 + lane];
    unsigned int q1 = t1q[(size_t)e1.x * 64 + lane];
    unsigned int q2 = t1q[(size_t)e2.x * 64 + lane];
    unsigned int q3 = t1q[(size_t)e3.x * 64 + lane];
    float w0 = __int_as_float(e0.y), w1 = __int_as_float(e1.y);
    float w2 = __int_as_float(e2.y), w3 = __int_as_float(e3.y);
    ax += w0 * bflo(q0) + w1 * bflo(q1) + w2 * bflo(q2) + w3 * bflo(q3);
    ay += w0 * bfhi(q0) + w1 * bfhi(q1) + w2 * bfhi(q2) + w3 * bfhi(q3);
  }
  for (; i < end; ++i) {
    int2 e = edges[i];
    unsigned int q = t1q[(size_t)e.x * 64 + lane];
    float w = __int_as_float(e.y);
    ax += w * bflo(q);
    ay += w * bfhi(q);
  }
  reinterpret_cast<float2*>(y)[(size_t)row * 64 + lane] =
      make_float2(fmaxf(ax, 0.f), fmaxf(ay, 0.f));
}

// ===========================================================================
// SpMM (64-wide, bf16 table) + row softmax. One wave per row, but each wave
// processes TWO edges at once: lanes 0-31 take edge i, lanes 32-63 edge i+1
// (each lane loads a packed uint = 2 bf16 cols -> 128B/edge coalesced).
// Partial accumulators merged with one shfl_xor(32), then 32-lane softmax
// reductions (both halves hold identical values).
// ===========================================================================
__global__ __launch_bounds__(256) void spmm_softmax_kernel(
    const int* __restrict__ rowptr, const int2* __restrict__ edges,
    const unsigned int* __restrict__ t2q,  // [N_NODES][32] packed bf16x2
    float* __restrict__ out) {
  const int row = blockIdx.x * 4 + (threadIdx.x >> 6);
  const int lane = threadIdx.x & 63;
  const int sub = lane >> 5;   // which edge of the pair
  const int sl = lane & 31;    // col pair index
  const int beg = rowptr[row];
  const int end = rowptr[row + 1];
  float ax = 0.f, ay = 0.f;
  int i = beg;
  for (; i + 4 <= end; i += 4) {
    int2 ea = edges[i + sub];
    int2 eb = edges[i + 2 + sub];
    unsigned int qa = t2q[(size_t)ea.x * 32 + sl];
    unsigned int qb = t2q[(size_t)eb.x * 32 + sl];
    float va = __int_as_float(ea.y), vb = __int_as_float(eb.y);
    ax += va * bflo(qa) + vb * bflo(qb);
    ay += va * bfhi(qa) + vb * bfhi(qb);
  }
  for (; i < end; i += 2) {
    int j = i + sub;
    bool ok = j < end;
    int2 e = edges[ok ? j : end - 1];
    float v = ok ? __int_as_float(e.y) : 0.f;
    unsigned int q = t2q[(size_t)e.x * 32 + sl];
    ax += v * bflo(q);
    ay += v * bfhi(q);
  }
  // merge the two per-edge halves (both halves now hold the full sum)
  ax += __shfl_xor(ax, 32);
  ay += __shfl_xor(ay, 32);
  // softmax over 64 cols = 32 lanes x 2
  float m = fmaxf(ax, ay);
  for (int o = 16; o >= 1; o >>= 1) m = fmaxf(m, __shfl_xor(m, o));
  float ex = expf(ax - m), ey = expf(ay - m);
  float s = ex + ey;
  for (int o = 16; o >= 1; o >>= 1) s += __shfl_xor(s, o);
  if (sub == 0)
    reinterpret_cast<float2*>(out)[(size_t)row * 32 + sl] =
        make_float2(ex / s, ey / s);
}

extern "C" void kernel_launch(void* const* d_in, const int* in_sizes, int n_in,
                              void* d_out, int out_size, void* d_ws, size_t ws_size,
                              hipStream_t stream) {
  const float* emb   = (const float*)d_in[0];
  const int*   arows = (const int*)d_in[1];
  const int*   acols = (const int*)d_in[2];
  const float* avals = (const float*)d_in[3];
  const float* W1    = (const float*)d_in[4];
  const float* W2    = (const float*)d_in[5];
  float* out = (float*)d_out;
  const int E = in_sizes[1];

  // ---- workspace layout (~58.3 MB) ----
  const size_t hbytes = (size_t)N_NODES * DIM * sizeof(float);  // 25.6 MB
  char* p = (char*)d_ws;
  char*  bufA   = p;         p += hbytes;                    // t1/t2 (bf16)
  float* bufB   = (float*)p; p += hbytes;                    // h (f32)
  int2*  edges  = (int2*)p;  p += (size_t)E * sizeof(int2);  // 6.4 MB
  int*   deg    = (int*)p;   p += (size_t)N_NODES * sizeof(int);
  int*   rowptr = (int*)p;
  // aliases: scan temps live in the (not yet written) edges buffer; per-edge
  // local offsets live in the (not yet written) h buffer.
  int* incl     = (int*)edges;
  int* partials = ((int*)edges) + N_NODES;
  int* localoff = (int*)bufB;

  hipMemsetAsync(deg, 0, (size_t)N_NODES * sizeof(int), stream);

  const int eblocks = (E + 255) / 256;

  // CSR build
  off_kernel<<<eblocks, 256, 0, stream>>>(arows, deg, localoff, E);
  scan_blk_kernel<<<SCAN_NB, 256, 0, stream>>>(deg, incl, partials);
  scan_part_kernel<<<1, 256, 0, stream>>>(partials, rowptr, E);
  scan_add_kernel<<<SCAN_NB, 256, 0, stream>>>(incl, deg, partials, rowptr);
  scatter_kernel<<<eblocks, 256, 0, stream>>>(arows, acols, avals, rowptr,
                                              localoff, edges, E);

  const int gblocks = (N_NODES + 63) / 64;  // 782

  // layer 1, reassociated: h = relu(A @ (emb @ W1)), t1 stored bf16
  gemm_kernel<128><<<dim3(gblocks, 2), 256, 0, stream>>>(
      emb, W1, (unsigned short*)bufA, N_NODES);
  spmm_relu_kernel<<<N_NODES / 4, 256, 0, stream>>>(
      rowptr, edges, (const unsigned int*)bufA, bufB);
  // layer 2, reassociated: out = softmax(A @ (h @ W2)), t2 stored bf16
  gemm_kernel<64><<<dim3(gblocks, 1), 256, 0, stream>>>(
      bufB, W2, (unsigned short*)bufA, N_NODES);
  spmm_softmax_kernel<<<N_NODES / 4, 256, 0, stream>>>(
      rowptr, edges, (const unsigned int*)bufA, out);
}

// Round 8
// 248.853 us; speedup vs baseline: 11.9473x; 1.0351x over previous
//
#include <hip/hip_runtime.h>
#include <cmath>

#define N_NODES 50000
#define DIM 128
#define DOUT 64
#define SCAN_NB 196  // ceil(50000/256)

typedef float f32x4 __attribute__((ext_vector_type(4)));

// f32 -> bf16 (round-to-nearest-even), packed as ushort
__device__ __forceinline__ unsigned short f2bf(float f) {
  unsigned int u = __float_as_uint(f);
  u = (u + 0x7fffu + ((u >> 16) & 1u)) >> 16;
  return (unsigned short)u;
}
// packed uint = [bf16 lo | bf16 hi] -> two floats
__device__ __forceinline__ float bflo(unsigned int q) {
  return __uint_as_float(q << 16);
}
__device__ __forceinline__ float bfhi(unsigned int q) {
  return __uint_as_float(q & 0xffff0000u);
}

// ===========================================================================
// CSR build: per-edge local offset (atomic hist) -> two-level scan -> scatter
// (no atomic in scatter: pos = rowptr[row] + localoff[e]).
// ===========================================================================

__global__ __launch_bounds__(256) void off_kernel(
    const int* __restrict__ rows, int* __restrict__ deg,
    int* __restrict__ localoff, int E) {
  int e = blockIdx.x * blockDim.x + threadIdx.x;
  if (e < E) localoff[e] = atomicAdd(&deg[rows[e]], 1);
}

// per-block inclusive scan of deg -> incl, block totals -> partials
__global__ __launch_bounds__(256) void scan_blk_kernel(
    const int* __restrict__ deg, int* __restrict__ incl,
    int* __restrict__ partials) {
  __shared__ int s[256];
  int i = blockIdx.x * 256 + threadIdx.x;
  int v = (i < N_NODES) ? deg[i] : 0;
  s[threadIdx.x] = v;
  __syncthreads();
  for (int o = 1; o < 256; o <<= 1) {
    int t = (threadIdx.x >= (unsigned)o) ? s[threadIdx.x - o] : 0;
    __syncthreads();
    s[threadIdx.x] += t;
    __syncthreads();
  }
  if (i < N_NODES) incl[i] = s[threadIdx.x];
  if (threadIdx.x == 255) partials[blockIdx.x] = s[255];
}

// single small block: exclusive-scan the 196 partials in place
__global__ __launch_bounds__(256) void scan_part_kernel(
    int* __restrict__ partials, int* __restrict__ rowptr, int E) {
  __shared__ int s[256];
  int v = (threadIdx.x < SCAN_NB) ? partials[threadIdx.x] : 0;
  s[threadIdx.x] = v;
  __syncthreads();
  for (int o = 1; o < 256; o <<= 1) {
    int t = (threadIdx.x >= (unsigned)o) ? s[threadIdx.x - o] : 0;
    __syncthreads();
    s[threadIdx.x] += t;
    __syncthreads();
  }
  if (threadIdx.x < SCAN_NB) partials[threadIdx.x] = s[threadIdx.x] - v;
  if (threadIdx.x == 0) rowptr[N_NODES] = E;
}

// exclusive prefix = incl - deg + block offset -> rowptr
__global__ __launch_bounds__(256) void scan_add_kernel(
    const int* __restrict__ incl, const int* __restrict__ deg,
    const int* __restrict__ partials, int* __restrict__ rowptr) {
  int i = blockIdx.x * 256 + threadIdx.x;
  if (i < N_NODES)
    rowptr[i] = incl[i] - deg[i] + partials[blockIdx.x];
}

__global__ __launch_bounds__(256) void scatter_kernel(
    const int* __restrict__ rows, const int* __restrict__ cols,
    const float* __restrict__ vals, const int* __restrict__ rowptr,
    const int* __restrict__ localoff, int2* __restrict__ edges, int E) {
  int e = blockIdx.x * blockDim.x + threadIdx.x;
  if (e < E) {
    int p = rowptr[rows[e]] + localoff[e];
    edges[p] = make_int2(cols[e], __float_as_int(vals[e]));
  }
}

// ===========================================================================
// Dense GEMM: y[M,N](bf16 packed) = x[M,128] @ W[128,N], N in {128,64}.
// XBF16: x rows are packed bf16x2 (64 uints); converted to f32 during LDS
// staging so the inner loop is unchanged. Block tile 64x64, thread 4x4,
// k-unroll 4: 64 FMA per 8 ds_read_b128. Pad 132 kills bank aliasing.
// ===========================================================================
template <int N, bool XBF16>
__global__ __launch_bounds__(256) void gemm_kernel(
    const void* __restrict__ xin, const float* __restrict__ W,
    unsigned short* __restrict__ y, int M) {
  __shared__ float sW[128 * 64];   // sW[k*64 + c]
  __shared__ float sX[64 * 132];   // sX[r*132 + k]
  const int cb = blockIdx.y;
  const int row0 = blockIdx.x * 64;

  for (int i = threadIdx.x; i < 128 * 16; i += 256) {
    int k = i >> 4, c4 = i & 15;
    reinterpret_cast<f32x4*>(sW)[k * 16 + c4] =
        reinterpret_cast<const f32x4*>(W)[k * (N / 4) + cb * 16 + c4];
  }
  if constexpr (XBF16) {
    const unsigned int* xq = (const unsigned int*)xin;
    for (int i = threadIdx.x; i < 64 * 16; i += 256) {
      int r = i >> 4, g = i & 15;  // g-th uint4 = 8 bf16 = cols 8g..8g+7
      int gr = row0 + r;
      if (gr >= M) gr = M - 1;
      uint4 q = reinterpret_cast<const uint4*>(xq + (size_t)gr * 64)[g];
      float* d = &sX[r * 132 + g * 8];
      d[0] = bflo(q.x); d[1] = bfhi(q.x);
      d[2] = bflo(q.y); d[3] = bfhi(q.y);
      d[4] = bflo(q.z); d[5] = bfhi(q.z);
      d[6] = bflo(q.w); d[7] = bfhi(q.w);
    }
  } else {
    const float* x = (const float*)xin;
    for (int i = threadIdx.x; i < 64 * 32; i += 256) {
      int r = i >> 5, c4 = i & 31;
      int gr = row0 + r;
      if (gr >= M) gr = M - 1;
      f32x4 v = reinterpret_cast<const f32x4*>(x + (size_t)gr * 128)[c4];
      *reinterpret_cast<f32x4*>(&sX[r * 132 + c4 * 4]) = v;
    }
  }
  __syncthreads();

  const int ct = threadIdx.x & 15;   // -> cols c0..c0+3
  const int rt = threadIdx.x >> 4;   // -> rows rt*4..rt*4+3
  const int c0 = ct * 4;
  float acc[4][4] = {};

  for (int k = 0; k < 128; k += 4) {
    f32x4 xa[4], wb[4];
#pragma unroll
    for (int r = 0; r < 4; ++r)
      xa[r] = *reinterpret_cast<const f32x4*>(&sX[(rt * 4 + r) * 132 + k]);
#pragma unroll
    for (int kk = 0; kk < 4; ++kk)
      wb[kk] = *reinterpret_cast<const f32x4*>(&sW[(k + kk) * 64 + c0]);
#pragma unroll
    for (int r = 0; r < 4; ++r)
#pragma unroll
      for (int c = 0; c < 4; ++c)
#pragma unroll
        for (int kk = 0; kk < 4; ++kk)
          acc[r][c] += xa[r][kk] * wb[kk][c];
  }

#pragma unroll
  for (int r = 0; r < 4; ++r) {
    int gr = row0 + rt * 4 + r;
    if (gr < M) {
      ushort4 v = {f2bf(acc[r][0]), f2bf(acc[r][1]),
                   f2bf(acc[r][2]), f2bf(acc[r][3])};
      *reinterpret_cast<ushort4*>(y + (size_t)gr * N + cb * 64 + c0) = v;
    }
  }
}

// ===========================================================================
// SpMM (128-wide, bf16 table) + ReLU -> h stored as packed bf16x2.
// One 64-lane wave per row; each lane loads a packed uint (2 bf16 cols):
// 256B/edge fully coalesced. Unroll 8: eight gathers in flight per wave.
// ===========================================================================
__global__ __launch_bounds__(256) void spmm_relu_kernel(
    const int* __restrict__ rowptr, const int2* __restrict__ edges,
    const unsigned int* __restrict__ t1q,  // [N_NODES][64] packed bf16x2
    unsigned int* __restrict__ hq) {       // [N_NODES][64] packed bf16x2
  const int row = blockIdx.x * 4 + (threadIdx.x >> 6);
  const int lane = threadIdx.x & 63;
  const int beg = rowptr[row];
  const int end = rowptr[row + 1];
  float ax = 0.f, ay = 0.f;
  int i = beg;
  for (; i + 8 <= end; i += 8) {
    int2 e0 = edges[i],     e1 = edges[i + 1], e2 = edges[i + 2], e3 = edges[i + 3];
    int2 e4 = edges[i + 4], e5 = edges[i + 5], e6 = edges[i + 6], e7 = edges[i + 7];
    unsigned int q0 = t1q[(size_t)e0.x * 64 + lane];
    unsigned int q1 = t1q[(size_t)e1.x * 64 + lane];
    unsigned int q2 = t1q[(size_t)e2.x * 64 + lane];
    unsigned int q3 = t1q[(size_t)e3.x * 64 + lane];
    unsigned int q4 = t1q[(size_t)e4.x * 64 + lane];
    unsigned int q5 = t1q[(size_t)e5.x * 64 + lane];
    unsigned int q6 = t1q[(size_t)e6.x * 64 + lane];
    unsigned int q7 = t1q[(size_t)e7.x * 64 + lane];
    float w0 = __int_as_float(e0.y), w1 = __int_as_float(e1.y);
    float w2 = __int_as_float(e2.y), w3 = __int_as_float(e3.y);
    float w4 = __int_as_float(e4.y), w5 = __int_as_float(e5.y);
    float w6 = __int_as_float(e6.y), w7 = __int_as_float(e7.y);
    ax += w0 * bflo(q0) + w1 * bflo(q1) + w2 * bflo(q2) + w3 * bflo(q3) +
          w4 * bflo(q4) + w5 * bflo(q5) + w6 * bflo(q6) + w7 * bflo(q7);
    ay += w0 * bfhi(q0) + w1 * bfhi(q1) + w2 * bfhi(q2) + w3 * bfhi(q3) +
          w4 * bfhi(q4) + w5 * bfhi(q5) + w6 * bfhi(q6) + w7 * bfhi(q7);
  }
  for (; i + 2 <= end; i += 2) {
    int2 e0 = edges[i], e1 = edges[i + 1];
    unsigned int q0 = t1q[(size_t)e0.x * 64 + lane];
    unsigned int q1 = t1q[(size_t)e1.x * 64 + lane];
    float w0 = __int_as_float(e0.y), w1 = __int_as_float(e1.y);
    ax += w0 * bflo(q0) + w1 * bflo(q1);
    ay += w0 * bfhi(q0) + w1 * bfhi(q1);
  }
  if (i < end) {
    int2 e = edges[i];
    unsigned int q = t1q[(size_t)e.x * 64 + lane];
    float w = __int_as_float(e.y);
    ax += w * bflo(q);
    ay += w * bfhi(q);
  }
  ax = fmaxf(ax, 0.f);
  ay = fmaxf(ay, 0.f);
  hq[(size_t)row * 64 + lane] =
      (unsigned int)f2bf(ax) | ((unsigned int)f2bf(ay) << 16);
}

// ===========================================================================
// SpMM (64-wide, bf16 table) + row softmax. One wave per row; lanes 0-31
// take even edges, lanes 32-63 odd edges (each lane loads a packed uint =
// 2 bf16 cols -> 128B/edge coalesced). Unroll: 8 edges/iter (4 per half).
// Halves merged with one shfl_xor(32), then 32-lane softmax reductions.
// ===========================================================================
__global__ __launch_bounds__(256) void spmm_softmax_kernel(
    const int* __restrict__ rowptr, const int2* __restrict__ edges,
    const unsigned int* __restrict__ t2q,  // [N_NODES][32] packed bf16x2
    float* __restrict__ out) {
  const int row = blockIdx.x * 4 + (threadIdx.x >> 6);
  const int lane = threadIdx.x & 63;
  const int sub = lane >> 5;   // which edge of the pair
  const int sl = lane & 31;    // col pair index
  const int beg = rowptr[row];
  const int end = rowptr[row + 1];
  float ax = 0.f, ay = 0.f;
  int i = beg;
  for (; i + 8 <= end; i += 8) {
    int2 ea = edges[i + sub];
    int2 eb = edges[i + 2 + sub];
    int2 ec = edges[i + 4 + sub];
    int2 ed = edges[i + 6 + sub];
    unsigned int qa = t2q[(size_t)ea.x * 32 + sl];
    unsigned int qb = t2q[(size_t)eb.x * 32 + sl];
    unsigned int qc = t2q[(size_t)ec.x * 32 + sl];
    unsigned int qd = t2q[(size_t)ed.x * 32 + sl];
    float va = __int_as_float(ea.y), vb = __int_as_float(eb.y);
    float vc = __int_as_float(ec.y), vd = __int_as_float(ed.y);
    ax += va * bflo(qa) + vb * bflo(qb) + vc * bflo(qc) + vd * bflo(qd);
    ay += va * bfhi(qa) + vb * bfhi(qb) + vc * bfhi(qc) + vd * bfhi(qd);
  }
  for (; i < end; i += 2) {
    int j = i + sub;
    bool ok = j < end;
    int2 e = edges[ok ? j : end - 1];
    float v = ok ? __int_as_float(e.y) : 0.f;
    unsigned int q = t2q[(size_t)e.x * 32 + sl];
    ax += v * bflo(q);
    ay += v * bfhi(q);
  }
  // merge the two per-edge halves (both halves now hold the full sum)
  ax += __shfl_xor(ax, 32);
  ay += __shfl_xor(ay, 32);
  // softmax over 64 cols = 32 lanes x 2
  float m = fmaxf(ax, ay);
  for (int o = 16; o >= 1; o >>= 1) m = fmaxf(m, __shfl_xor(m, o));
  float ex = expf(ax - m), ey = expf(ay - m);
  float s = ex + ey;
  for (int o = 16; o >= 1; o >>= 1) s += __shfl_xor(s, o);
  if (sub == 0)
    reinterpret_cast<float2*>(out)[(size_t)row * 32 + sl] =
        make_float2(ex / s, ey / s);
}

extern "C" void kernel_launch(void* const* d_in, const int* in_sizes, int n_in,
                              void* d_out, int out_size, void* d_ws, size_t ws_size,
                              hipStream_t stream) {
  const float* emb   = (const float*)d_in[0];
  const int*   arows = (const int*)d_in[1];
  const int*   acols = (const int*)d_in[2];
  const float* avals = (const float*)d_in[3];
  const float* W1    = (const float*)d_in[4];
  const float* W2    = (const float*)d_in[5];
  float* out = (float*)d_out;
  const int E = in_sizes[1];

  // ---- workspace layout ----
  const size_t hbytes = (size_t)N_NODES * DIM * sizeof(float);  // 25.6 MB
  char* p = (char*)d_ws;
  char*  bufA   = p;         p += hbytes;                    // t1/t2 (bf16)
  char*  bufB   = p;         p += hbytes;                    // h (bf16) / localoff
  int2*  edges  = (int2*)p;  p += (size_t)E * sizeof(int2);  // 6.4 MB
  int*   deg    = (int*)p;   p += (size_t)N_NODES * sizeof(int);
  int*   rowptr = (int*)p;
  // aliases: scan temps live in the (not yet written) edges buffer; per-edge
  // local offsets live in the (not yet written) h buffer.
  int* incl     = (int*)edges;
  int* partials = ((int*)edges) + N_NODES;
  int* localoff = (int*)bufB;

  hipMemsetAsync(deg, 0, (size_t)N_NODES * sizeof(int), stream);

  const int eblocks = (E + 255) / 256;

  // CSR build
  off_kernel<<<eblocks, 256, 0, stream>>>(arows, deg, localoff, E);
  scan_blk_kernel<<<SCAN_NB, 256, 0, stream>>>(deg, incl, partials);
  scan_part_kernel<<<1, 256, 0, stream>>>(partials, rowptr, E);
  scan_add_kernel<<<SCAN_NB, 256, 0, stream>>>(incl, deg, partials, rowptr);
  scatter_kernel<<<eblocks, 256, 0, stream>>>(arows, acols, avals, rowptr,
                                              localoff, edges, E);

  const int gblocks = (N_NODES + 63) / 64;  // 782

  // layer 1, reassociated: h = relu(A @ (emb @ W1)), t1 stored bf16
  gemm_kernel<128, false><<<dim3(gblocks, 2), 256, 0, stream>>>(
      emb, W1, (unsigned short*)bufA, N_NODES);
  spmm_relu_kernel<<<N_NODES / 4, 256, 0, stream>>>(
      rowptr, edges, (const unsigned int*)bufA, (unsigned int*)bufB);
  // layer 2, reassociated: out = softmax(A @ (h @ W2)), h read as bf16
  gemm_kernel<64, true><<<dim3(gblocks, 1), 256, 0, stream>>>(
      bufB, W2, (unsigned short*)bufA, N_NODES);
  spmm_softmax_kernel<<<N_NODES / 4, 256, 0, stream>>>(
      rowptr, edges, (const unsigned int*)bufA, out);
}

// Round 11
// 232.681 us; speedup vs baseline: 12.7777x; 1.0695x over previous
//
#include <hip/hip_runtime.h>
#include <cmath>

#define N_NODES 50000
#define DIM 128
#define DOUT 64
#define SCAN_NB 196  // ceil(50000/256)

typedef float f32x4 __attribute__((ext_vector_type(4)));
typedef short bf16x8 __attribute__((ext_vector_type(8)));
typedef float f32x4v __attribute__((ext_vector_type(4)));

// f32 -> bf16 (round-to-nearest-even), as ushort
__device__ __forceinline__ unsigned short f2bf(float f) {
  unsigned int u = __float_as_uint(f);
  u = (u + 0x7fffu + ((u >> 16) & 1u)) >> 16;
  return (unsigned short)u;
}
__device__ __forceinline__ float bf2f(unsigned short h) {
  return __uint_as_float((unsigned int)h << 16);
}
// packed uint = [bf16 lo | bf16 hi] -> two floats
__device__ __forceinline__ float bflo(unsigned int q) {
  return __uint_as_float(q << 16);
}
__device__ __forceinline__ float bfhi(unsigned int q) {
  return __uint_as_float(q & 0xffff0000u);
}

// ===========================================================================
// CSR build: per-edge local offset (atomic hist) -> two-level scan -> scatter
// ===========================================================================

__global__ __launch_bounds__(256) void off_kernel(
    const int* __restrict__ rows, int* __restrict__ deg,
    int* __restrict__ localoff, int E) {
  int e = blockIdx.x * blockDim.x + threadIdx.x;
  if (e < E) localoff[e] = atomicAdd(&deg[rows[e]], 1);
}

__global__ __launch_bounds__(256) void scan_blk_kernel(
    const int* __restrict__ deg, int* __restrict__ incl,
    int* __restrict__ partials) {
  __shared__ int s[256];
  int i = blockIdx.x * 256 + threadIdx.x;
  int v = (i < N_NODES) ? deg[i] : 0;
  s[threadIdx.x] = v;
  __syncthreads();
  for (int o = 1; o < 256; o <<= 1) {
    int t = (threadIdx.x >= (unsigned)o) ? s[threadIdx.x - o] : 0;
    __syncthreads();
    s[threadIdx.x] += t;
    __syncthreads();
  }
  if (i < N_NODES) incl[i] = s[threadIdx.x];
  if (threadIdx.x == 255) partials[blockIdx.x] = s[255];
}

__global__ __launch_bounds__(256) void scan_part_kernel(
    int* __restrict__ partials, int* __restrict__ rowptr, int E) {
  __shared__ int s[256];
  int v = (threadIdx.x < SCAN_NB) ? partials[threadIdx.x] : 0;
  s[threadIdx.x] = v;
  __syncthreads();
  for (int o = 1; o < 256; o <<= 1) {
    int t = (threadIdx.x >= (unsigned)o) ? s[threadIdx.x - o] : 0;
    __syncthreads();
    s[threadIdx.x] += t;
    __syncthreads();
  }
  if (threadIdx.x < SCAN_NB) partials[threadIdx.x] = s[threadIdx.x] - v;
  if (threadIdx.x == 0) rowptr[N_NODES] = E;
}

__global__ __launch_bounds__(256) void scan_add_kernel(
    const int* __restrict__ incl, const int* __restrict__ deg,
    const int* __restrict__ partials, int* __restrict__ rowptr) {
  int i = blockIdx.x * 256 + threadIdx.x;
  if (i < N_NODES)
    rowptr[i] = incl[i] - deg[i] + partials[blockIdx.x];
}

__global__ __launch_bounds__(256) void scatter_kernel(
    const int* __restrict__ rows, const int* __restrict__ cols,
    const float* __restrict__ vals, const int* __restrict__ rowptr,
    const int* __restrict__ localoff, int2* __restrict__ edges, int E) {
  int e = blockIdx.x * blockDim.x + threadIdx.x;
  if (e < E) {
    int p = rowptr[rows[e]] + localoff[e];
    edges[p] = make_int2(cols[e], __float_as_int(vals[e]));
  }
}

// ===========================================================================
// W transpose + bf16 hi/lo split (once per launch, tiny):
// Wt[c][k] = W[k][c]; hi = bf16(w), lo = bf16(w - hi).
// ===========================================================================
__global__ __launch_bounds__(256) void wtrans_kernel(
    const float* __restrict__ W1, const float* __restrict__ W2,
    unsigned short* __restrict__ W1th, unsigned short* __restrict__ W1tl,
    unsigned short* __restrict__ W2th, unsigned short* __restrict__ W2tl) {
  int i = blockIdx.x * 256 + threadIdx.x;
  if (i < 128 * 128) {
    int c = i >> 7, k = i & 127;
    float v = W1[k * 128 + c];
    unsigned short h = f2bf(v);
    W1th[i] = h;
    W1tl[i] = f2bf(v - bf2f(h));
  } else if (i < 128 * 128 + 64 * 128) {
    int j = i - 128 * 128;
    int c = j >> 7, k = j & 127;
    float v = W2[k * 64 + c];
    unsigned short h = f2bf(v);
    W2th[j] = h;
    W2tl[j] = f2bf(v - bf2f(h));
  }
}

// ===========================================================================
// MFMA GEMM: y[M,N](bf16) = x[M,128] @ W[128,N], N in {128,64}.
// Split-precision: x = xhi+xlo (bf16 each, only if XSPLIT: x is f32),
// W = Whi+Wlo. t = xhi@Whi + xlo@Whi + xhi@Wlo  (lo*lo dropped, ~2^-18).
// Keeps f32-grade input accuracy while using 16x16x32 bf16 MFMA.
//
// Block: 256 thr = 4 waves; tile 64 rows x 64 cols; wave w owns rows w*16..+15,
// computes 4 n-subtiles of 16x16 with K=128 (4 MFMA k-steps).
// Fragment mapping (m89-verified): A row=lane&15, k=(lane>>4)*8+j;
// B col=lane&15, same k; D col=lane&15, row=(lane>>4)*4+reg.
// LDS rows padded to 136 bf16 (272B = 17x16B): 16B-aligned, even slot spread.
// ===========================================================================
template <int N, bool XSPLIT>
__global__ __launch_bounds__(256) void gemm_mfma_kernel(
    const void* __restrict__ xin,            // XSPLIT ? f32 [M][128] : bf16 packed
    const unsigned short* __restrict__ Wth,  // bf16 [N][128] (= W^T hi)
    const unsigned short* __restrict__ Wtl,  // bf16 [N][128] (= W^T lo)
    unsigned short* __restrict__ y,          // bf16 [M][N]
    int M) {
  __shared__ unsigned short sXh[64 * 136];
  __shared__ unsigned short sXl[XSPLIT ? 64 * 136 : 1];
  __shared__ unsigned short sWh[64 * 136];
  __shared__ unsigned short sWl[64 * 136];
  const int cb = blockIdx.y;
  const int row0 = blockIdx.x * 64;
  const int tid = threadIdx.x;

  // ---- stage x tile ----
  if constexpr (XSPLIT) {
    const float* x = (const float*)xin;
    for (int i = tid; i < 64 * 16; i += 256) {
      int r = i >> 4, g = i & 15;  // g-th group of 8 cols
      int gr = row0 + r; if (gr >= M) gr = M - 1;
      const f32x4* src = reinterpret_cast<const f32x4*>(x + (size_t)gr * 128 + g * 8);
      f32x4 a = src[0], b = src[1];
      unsigned short* dh = &sXh[r * 136 + g * 8];
      unsigned short* dl = &sXl[r * 136 + g * 8];
      float v[8] = {a.x, a.y, a.z, a.w, b.x, b.y, b.z, b.w};
#pragma unroll
      for (int j = 0; j < 8; ++j) {
        unsigned short h = f2bf(v[j]);
        dh[j] = h;
        dl[j] = f2bf(v[j] - bf2f(h));
      }
    }
  } else {
    const uint4* xq = (const uint4*)xin;  // bf16 rows = 16 uint4
    for (int i = tid; i < 64 * 16; i += 256) {
      int r = i >> 4, g = i & 15;
      int gr = row0 + r; if (gr >= M) gr = M - 1;
      *reinterpret_cast<uint4*>(&sXh[r * 136 + g * 8]) = xq[(size_t)gr * 16 + g];
    }
  }
  // ---- stage W tiles (rows cb*64..+64 of Wt) ----
  {
    const uint4* wh = (const uint4*)Wth;
    const uint4* wl = (const uint4*)Wtl;
    for (int i = tid; i < 64 * 16; i += 256) {
      int c = i >> 4, g = i & 15;
      size_t src = (size_t)(cb * 64 + c) * 16 + g;
      *reinterpret_cast<uint4*>(&sWh[c * 136 + g * 8]) = wh[src];
      *reinterpret_cast<uint4*>(&sWl[c * 136 + g * 8]) = wl[src];
    }
  }
  __syncthreads();

  const int lane = tid & 63;
  const int w = tid >> 6;      // wave -> rows w*16..+15
  const int r = lane & 15;
  const int q = lane >> 4;

  bf16x8 ah[4], al[4];
#pragma unroll
  for (int k = 0; k < 4; ++k) {
    ah[k] = *reinterpret_cast<const bf16x8*>(&sXh[(w * 16 + r) * 136 + k * 32 + q * 8]);
    if constexpr (XSPLIT)
      al[k] = *reinterpret_cast<const bf16x8*>(&sXl[(w * 16 + r) * 136 + k * 32 + q * 8]);
  }

  f32x4v acc[4] = {{0.f,0.f,0.f,0.f},{0.f,0.f,0.f,0.f},{0.f,0.f,0.f,0.f},{0.f,0.f,0.f,0.f}};
#pragma unroll
  for (int k = 0; k < 4; ++k) {
#pragma unroll
    for (int n = 0; n < 4; ++n) {
      bf16x8 bh = *reinterpret_cast<const bf16x8*>(&sWh[(n * 16 + r) * 136 + k * 32 + q * 8]);
      bf16x8 bl = *reinterpret_cast<const bf16x8*>(&sWl[(n * 16 + r) * 136 + k * 32 + q * 8]);
      acc[n] = __builtin_amdgcn_mfma_f32_16x16x32_bf16(ah[k], bh, acc[n], 0, 0, 0);
      acc[n] = __builtin_amdgcn_mfma_f32_16x16x32_bf16(ah[k], bl, acc[n], 0, 0, 0);
      if constexpr (XSPLIT)
        acc[n] = __builtin_amdgcn_mfma_f32_16x16x32_bf16(al[k], bh, acc[n], 0, 0, 0);
    }
  }

  // ---- epilogue: D col = lane&15, row = (lane>>4)*4 + j ----
#pragma unroll
  for (int n = 0; n < 4; ++n) {
#pragma unroll
    for (int j = 0; j < 4; ++j) {
      int gr = row0 + w * 16 + q * 4 + j;
      if (gr < M)
        y[(size_t)gr * N + cb * 64 + n * 16 + r] = f2bf(acc[n][j]);
    }
  }
}

// ===========================================================================
// SpMM (128-wide, bf16 table) + ReLU -> h stored as packed bf16x2.
// One 64-lane wave per row; lane loads a packed uint (2 bf16 cols):
// 256B/edge coalesced. Unroll 8: eight gathers in flight per wave.
// ===========================================================================
__global__ __launch_bounds__(256) void spmm_relu_kernel(
    const int* __restrict__ rowptr, const int2* __restrict__ edges,
    const unsigned int* __restrict__ t1q,  // [N_NODES][64] packed bf16x2
    unsigned int* __restrict__ hq) {       // [N_NODES][64] packed bf16x2
  const int row = blockIdx.x * 4 + (threadIdx.x >> 6);
  const int lane = threadIdx.x & 63;
  const int beg = rowptr[row];
  const int end = rowptr[row + 1];
  float ax = 0.f, ay = 0.f;
  int i = beg;
  for (; i + 8 <= end; i += 8) {
    int2 e0 = edges[i],     e1 = edges[i + 1], e2 = edges[i + 2], e3 = edges[i + 3];
    int2 e4 = edges[i + 4], e5 = edges[i + 5], e6 = edges[i + 6], e7 = edges[i + 7];
    unsigned int q0 = t1q[(size_t)e0.x * 64 + lane];
    unsigned int q1 = t1q[(size_t)e1.x * 64 + lane];
    unsigned int q2 = t1q[(size_t)e2.x * 64 + lane];
    unsigned int q3 = t1q[(size_t)e3.x * 64 + lane];
    unsigned int q4 = t1q[(size_t)e4.x * 64 + lane];
    unsigned int q5 = t1q[(size_t)e5.x * 64 + lane];
    unsigned int q6 = t1q[(size_t)e6.x * 64 + lane];
    unsigned int q7 = t1q[(size_t)e7.x * 64 + lane];
    float w0 = __int_as_float(e0.y), w1 = __int_as_float(e1.y);
    float w2 = __int_as_float(e2.y), w3 = __int_as_float(e3.y);
    float w4 = __int_as_float(e4.y), w5 = __int_as_float(e5.y);
    float w6 = __int_as_float(e6.y), w7 = __int_as_float(e7.y);
    ax += w0 * bflo(q0) + w1 * bflo(q1) + w2 * bflo(q2) + w3 * bflo(q3) +
          w4 * bflo(q4) + w5 * bflo(q5) + w6 * bflo(q6) + w7 * bflo(q7);
    ay += w0 * bfhi(q0) + w1 * bfhi(q1) + w2 * bfhi(q2) + w3 * bfhi(q3) +
          w4 * bfhi(q4) + w5 * bfhi(q5) + w6 * bfhi(q6) + w7 * bfhi(q7);
  }
  for (; i + 2 <= end; i += 2) {
    int2 e0 = edges[i], e1 = edges[i + 1];
    unsigned int q0 = t1q[(size_t)e0.x * 64 + lane];
    unsigned int q1 = t1q[(size_t)e1.x * 64 + lane];
    float w0 = __int_as_float(e0.y), w1 = __int_as_float(e1.y);
    ax += w0 * bflo(q0) + w1 * bflo(q1);
    ay += w0 * bfhi(q0) + w1 * bfhi(q1);
  }
  if (i < end) {
    int2 e = edges[i];
    unsigned int q = t1q[(size_t)e.x * 64 + lane];
    float w = __int_as_float(e.y);
    ax += w * bflo(q);
    ay += w * bfhi(q);
  }
  ax = fmaxf(ax, 0.f);
  ay = fmaxf(ay, 0.f);
  hq[(size_t)row * 64 + lane] =
      (unsigned int)f2bf(ax) | ((unsigned int)f2bf(ay) << 16);
}

// ===========================================================================
// SpMM (64-wide, bf16 table) + row softmax. One wave per row; lanes 0-31
// take even edges, lanes 32-63 odd edges (packed uint = 2 bf16 cols ->
// 128B/edge coalesced). Unroll 8 edges/iter (4 per half). Halves merged with
// one shfl_xor(32), then 32-lane softmax reductions.
// ===========================================================================
__global__ __launch_bounds__(256) void spmm_softmax_kernel(
    const int* __restrict__ rowptr, const int2* __restrict__ edges,
    const unsigned int* __restrict__ t2q,  // [N_NODES][32] packed bf16x2
    float* __restrict__ out) {
  const int row = blockIdx.x * 4 + (threadIdx.x >> 6);
  const int lane = threadIdx.x & 63;
  const int sub = lane >> 5;
  const int sl = lane & 31;
  const int beg = rowptr[row];
  const int end = rowptr[row + 1];
  float ax = 0.f, ay = 0.f;
  int i = beg;
  for (; i + 8 <= end; i += 8) {
    int2 ea = edges[i + sub];
    int2 eb = edges[i + 2 + sub];
    int2 ec = edges[i + 4 + sub];
    int2 ed = edges[i + 6 + sub];
    unsigned int qa = t2q[(size_t)ea.x * 32 + sl];
    unsigned int qb = t2q[(size_t)eb.x * 32 + sl];
    unsigned int qc = t2q[(size_t)ec.x * 32 + sl];
    unsigned int qd = t2q[(size_t)ed.x * 32 + sl];
    float va = __int_as_float(ea.y), vb = __int_as_float(eb.y);
    float vc = __int_as_float(ec.y), vd = __int_as_float(ed.y);
    ax += va * bflo(qa) + vb * bflo(qb) + vc * bflo(qc) + vd * bflo(qd);
    ay += va * bfhi(qa) + vb * bfhi(qb) + vc * bfhi(qc) + vd * bfhi(qd);
  }
  for (; i < end; i += 2) {
    int j = i + sub;
    bool ok = j < end;
    int2 e = edges[ok ? j : end - 1];
    float v = ok ? __int_as_float(e.y) : 0.f;
    unsigned int q = t2q[(size_t)e.x * 32 + sl];
    ax += v * bflo(q);
    ay += v * bfhi(q);
  }
  ax += __shfl_xor(ax, 32);
  ay += __shfl_xor(ay, 32);
  float m = fmaxf(ax, ay);
  for (int o = 16; o >= 1; o >>= 1) m = fmaxf(m, __shfl_xor(m, o));
  float ex = expf(ax - m), ey = expf(ay - m);
  float s = ex + ey;
  for (int o = 16; o >= 1; o >>= 1) s += __shfl_xor(s, o);
  if (sub == 0)
    reinterpret_cast<float2*>(out)[(size_t)row * 32 + sl] =
        make_float2(ex / s, ey / s);
}

extern "C" void kernel_launch(void* const* d_in, const int* in_sizes, int n_in,
                              void* d_out, int out_size, void* d_ws, size_t ws_size,
                              hipStream_t stream) {
  const float* emb   = (const float*)d_in[0];
  const int*   arows = (const int*)d_in[1];
  const int*   acols = (const int*)d_in[2];
  const float* avals = (const float*)d_in[3];
  const float* W1    = (const float*)d_in[4];
  const float* W2    = (const float*)d_in[5];
  float* out = (float*)d_out;
  const int E = in_sizes[1];

  // ---- workspace layout ----
  const size_t hbytes = (size_t)N_NODES * DIM * sizeof(float);  // 25.6 MB
  char* p = (char*)d_ws;
  char*  bufA   = p;         p += hbytes;                    // t1/t2 (bf16)
  char*  bufB   = p;         p += hbytes;                    // h (bf16) / localoff
  int2*  edges  = (int2*)p;  p += (size_t)E * sizeof(int2);  // 6.4 MB
  int*   deg    = (int*)p;   p += (size_t)N_NODES * sizeof(int);
  int*   rowptr = (int*)p;   p += (size_t)(N_NODES + 1) * sizeof(int);
  unsigned short* W1th = (unsigned short*)p; p += 128 * 128 * 2;
  unsigned short* W1tl = (unsigned short*)p; p += 128 * 128 * 2;
  unsigned short* W2th = (unsigned short*)p; p += 64 * 128 * 2;
  unsigned short* W2tl = (unsigned short*)p; p += 64 * 128 * 2;
  // aliases: scan temps live in the (not yet written) edges buffer; per-edge
  // local offsets live in the (not yet written) h buffer.
  int* incl     = (int*)edges;
  int* partials = ((int*)edges) + N_NODES;
  int* localoff = (int*)bufB;

  hipMemsetAsync(deg, 0, (size_t)N_NODES * sizeof(int), stream);

  const int eblocks = (E + 255) / 256;

  // W transpose + hi/lo split (independent of CSR build)
  wtrans_kernel<<<96, 256, 0, stream>>>(W1, W2, W1th, W1tl, W2th, W2tl);

  // CSR build
  off_kernel<<<eblocks, 256, 0, stream>>>(arows, deg, localoff, E);
  scan_blk_kernel<<<SCAN_NB, 256, 0, stream>>>(deg, incl, partials);
  scan_part_kernel<<<1, 256, 0, stream>>>(partials, rowptr, E);
  scan_add_kernel<<<SCAN_NB, 256, 0, stream>>>(incl, deg, partials, rowptr);
  scatter_kernel<<<eblocks, 256, 0, stream>>>(arows, acols, avals, rowptr,
                                              localoff, edges, E);

  const int gblocks = (N_NODES + 63) / 64;  // 782

  // layer 1: t1 = emb @ W1 (split-precision MFMA), h = relu(A @ t1)
  gemm_mfma_kernel<128, true><<<dim3(gblocks, 2), 256, 0, stream>>>(
      emb, W1th, W1tl, (unsigned short*)bufA, N_NODES);
  spmm_relu_kernel<<<N_NODES / 4, 256, 0, stream>>>(
      rowptr, edges, (const unsigned int*)bufA, (unsigned int*)bufB);
  // layer 2: t2 = h @ W2 (W-split MFMA; h exactly bf16), out = softmax(A @ t2)
  gemm_mfma_kernel<64, false><<<dim3(gblocks, 1), 256, 0, stream>>>(
      bufB, W2th, W2tl, (unsigned short*)bufA, N_NODES);
  spmm_softmax_kernel<<<N_NODES / 4, 256, 0, stream>>>(
      rowptr, edges, (const unsigned int*)bufA, out);
}